// Round 6
// baseline (256.957 us; speedup 1.0000x reference)
//
#include <hip/hip_runtime.h>

// SGC: out = A_norm^2 (x W) + bias   (linearity: A^2 x W = A^2 (xW)).
// N=100000 nodes, E=1000000 edges, D=64 features, fp32 in/out.
// CSR build = two-level LDS-binned counting sort, ZERO per-edge global
// atomics (round-5 k_scatter showed 66MB writeback + 22G/s atomic wall).
//   kA_count: per-block LDS hist over 196 coarse buckets -> bc[bucket][block]
//   kA_scan : per-bucket prefix over blocks + bucket base scan
//   kA_place: LDS-staged bucket-major placement, coalesced run flush -> tmp
//   kB_sort : per-bucket fine sort (512-node range) -> ecw + start[] + dinv
// Hops: atomic-free gathers, bf16 intermediates, ecw-stream pipelining.

constexpr int kN = 100000;
constexpr int kD = 64;
constexpr int BSHIFT = 9;                    // 512 nodes per coarse bucket
constexpr int NBUCK = (kN + 511) >> BSHIFT;  // 196
constexpr int CHUNK = 4096;                  // pass-A edges per block

__device__ __forceinline__ float bf2f(unsigned short u) {
    return __uint_as_float(((unsigned)u) << 16);
}
__device__ __forceinline__ unsigned short f2bf(float f) {  // RNE
    unsigned b = __float_as_uint(f);
    b += 0x7FFF + ((b >> 16) & 1);
    return (unsigned short)(b >> 16);
}

// ---- pass A1: per-block bucket histogram (no global atomics) ----
__global__ __launch_bounds__(256) void kA_count(const int* __restrict__ row,
                                                int* __restrict__ bc, int nblk, int E) {
    __shared__ int hist[256];
    int t = threadIdx.x;
    hist[t] = 0;
    __syncthreads();
    int g0 = blockIdx.x * CHUNK;
    int n = min(CHUNK, E - g0);
    for (int i = t; i < n; i += 256) {
        atomicAdd(&hist[row[g0 + i] >> BSHIFT], 1);
    }
    __syncthreads();
    if (t < NBUCK) bc[t * nblk + blockIdx.x] = hist[t];
}

// ---- pass A2: bc[b][*] -> exclusive prefix over blocks; base[b] = bucket base
__global__ __launch_bounds__(256) void kA_scan(int* __restrict__ bc,
                                               int* __restrict__ base, int nblk) {
    __shared__ int tot[256];
    int b = threadIdx.x;
    int running = 0;
    if (b < NBUCK) {
        for (int k = 0; k < nblk; ++k) {
            int v = bc[b * nblk + k];
            bc[b * nblk + k] = running;
            running += v;
        }
    }
    tot[b] = (b < NBUCK) ? running : 0;
    __syncthreads();
    int v = tot[b];
    for (int off = 1; off < 256; off <<= 1) {
        int add = (b >= off) ? tot[b - off] : 0;
        __syncthreads();
        tot[b] += add;
        __syncthreads();
    }
    if (b < NBUCK) base[b] = tot[b] - v;  // exclusive bucket base
}

// ---- pass A3: bucket-major placement via LDS staging, coalesced run flush
// tmp[pos] = { col | (row&511)<<17 , w_bits }
__global__ __launch_bounds__(256) void kA_place(const int* __restrict__ row,
                                                const int* __restrict__ col,
                                                const float* __restrict__ w,
                                                const int* __restrict__ bc,
                                                const int* __restrict__ base, int nblk,
                                                int2* __restrict__ tmp, int E) {
    __shared__ int hist[256];
    __shared__ int lbase[256];
    __shared__ int gb[256];
    __shared__ int cur[256];
    __shared__ int2 stage[CHUNK];
    __shared__ unsigned char bkt[CHUNK];
    int t = threadIdx.x;
    hist[t] = 0;
    __syncthreads();
    int g0 = blockIdx.x * CHUNK;
    int n = min(CHUNK, E - g0);
    for (int i = t; i < n; i += 256) {
        atomicAdd(&hist[row[g0 + i] >> BSHIFT], 1);
    }
    __syncthreads();
    // exclusive scan hist -> lbase (local bucket starts within this chunk)
    int v = hist[t];
    lbase[t] = v;
    __syncthreads();
    for (int off = 1; off < 256; off <<= 1) {
        int add = (t >= off) ? lbase[t - off] : 0;
        __syncthreads();
        lbase[t] += add;
        __syncthreads();
    }
    int excl = lbase[t] - v;
    __syncthreads();
    lbase[t] = excl;
    cur[t] = excl;
    if (t < NBUCK) gb[t] = base[t] + bc[t * nblk + blockIdx.x];  // this block's run start
    __syncthreads();
    // place edges bucket-major in LDS (LDS atomics only)
    for (int i = t; i < n; i += 256) {
        int r = row[g0 + i];
        int c = col[g0 + i];
        float wv = w[g0 + i];
        int b = r >> BSHIFT;
        int lp = atomicAdd(&cur[b], 1);
        stage[lp] = make_int2(c | ((r & 511) << 17), __float_as_int(wv));
        bkt[lp] = (unsigned char)b;
    }
    __syncthreads();
    // flush: consecutive i within a bucket run -> consecutive global addresses
    for (int i = t; i < n; i += 256) {
        int b = bkt[i];
        tmp[gb[b] + (i - lbase[b])] = stage[i];
    }
}

// ---- pass B: per-bucket fine counting sort + start[] + fused deg/dinv ----
__global__ __launch_bounds__(512) void kB_sort(const int2* __restrict__ tmp,
                                               const int* __restrict__ base,
                                               int2* __restrict__ ecw,
                                               int* __restrict__ start,
                                               float* __restrict__ dinv, int E) {
    __shared__ int hist[512];
    __shared__ int lstart[512];
    __shared__ int cur[512];
    int b = blockIdx.x;
    int t = threadIdx.x;
    int gbase = base[b];
    int gend = (b == NBUCK - 1) ? E : base[b + 1];
    int size = gend - gbase;
    int node0 = b << BSHIFT;
    int nloc = min(512, kN - node0);
    hist[t] = 0;
    __syncthreads();
    for (int i = t; i < size; i += 512) {
        atomicAdd(&hist[(tmp[gbase + i].x >> 17) & 511], 1);
    }
    __syncthreads();
    // exclusive scan hist -> lstart
    int v = hist[t];
    lstart[t] = v;
    __syncthreads();
    for (int off = 1; off < 512; off <<= 1) {
        int add = (t >= off) ? lstart[t - off] : 0;
        __syncthreads();
        lstart[t] += add;
        __syncthreads();
    }
    int excl = lstart[t] - v;
    __syncthreads();
    lstart[t] = excl;
    cur[t] = excl;
    __syncthreads();
    if (t < nloc) start[node0 + t] = gbase + excl;
    if (b == 0 && t == 0) start[kN] = E;
    // scatter within bucket (writes stay in one XCD's L2 -> no amplification)
    for (int i = t; i < size; i += 512) {
        int2 e = tmp[gbase + i];
        int rl = (e.x >> 17) & 511;
        int lp = atomicAdd(&cur[rl], 1);
        ecw[gbase + lp] = make_int2(e.x & 0x1FFFF, e.y);
    }
    __syncthreads();
    // fused deg: dinv = rsqrt(1 + sum w) over this node's (L2-hot) segment
    if (t < nloc) {
        int s = gbase + lstart[t];
        int eend = s + hist[t];
        float d = 1.0f;
        for (int j = s; j < eend; ++j) d += __int_as_float(ecw[j].y);
        dinv[node0 + t] = (d > 0.0f) ? rsqrtf(d) : 0.0f;
    }
}

// ---- y = x @ W  (fp32 in, bf16 out). thread = row, W staged in LDS. ----
__global__ __launch_bounds__(256) void k_xw(const float* __restrict__ x,
                                            const float* __restrict__ W,
                                            unsigned short* __restrict__ y, int n) {
    __shared__ float Ws[kD * kD];
    for (int i = threadIdx.x; i < kD * kD; i += 256) Ws[i] = W[i];
    __syncthreads();
    int r = blockIdx.x * 256 + threadIdx.x;
    if (r >= n) return;
    float hr[kD];
    const float4* hp = reinterpret_cast<const float4*>(x + (size_t)r * kD);
#pragma unroll
    for (int k4 = 0; k4 < kD / 4; ++k4) {
        float4 v = hp[k4];
        hr[k4 * 4 + 0] = v.x;
        hr[k4 * 4 + 1] = v.y;
        hr[k4 * 4 + 2] = v.z;
        hr[k4 * 4 + 3] = v.w;
    }
    ushort4* op = reinterpret_cast<ushort4*>(y + (size_t)r * kD);
#pragma unroll
    for (int jb = 0; jb < kD / 4; ++jb) {
        float a0 = 0.0f, a1 = 0.0f, a2 = 0.0f, a3 = 0.0f;
#pragma unroll
        for (int k = 0; k < kD; ++k) {
            float hv = hr[k];
            a0 = fmaf(hv, Ws[k * kD + jb * 4 + 0], a0);
            a1 = fmaf(hv, Ws[k * kD + jb * 4 + 1], a1);
            a2 = fmaf(hv, Ws[k * kD + jb * 4 + 2], a2);
            a3 = fmaf(hv, Ws[k * kD + jb * 4 + 3], a3);
        }
        ushort4 o;
        o.x = f2bf(a0); o.y = f2bf(a1); o.z = f2bf(a2); o.w = f2bf(a3);
        op[jb] = o;
    }
}

// ---- software-pipelined gather hop body: 1 wave/node, lane=feature ----
template <typename OutWriter>
__device__ __forceinline__ void hop_body(const int* __restrict__ start,
                                         const int2* __restrict__ ecw,
                                         const float* __restrict__ dinv,
                                         const unsigned short* __restrict__ h_in,
                                         int n, OutWriter writeout) {
    int node = blockIdx.x * 4 + (threadIdx.x >> 6);
    int lane = threadIdx.x & 63;
    if (node >= n) return;  // wave-uniform (1 wave = 1 node)
    float di = dinv[node];
    float self = bf2f(h_in[(size_t)node * kD + lane]);
    float acc = di * self;
    int s = start[node], e = start[node + 1];
    int j = s;
    int rem = e - s;
    int2 a0, a1, a2, a3;
    if (rem >= 4) { a0 = ecw[j]; a1 = ecw[j + 1]; a2 = ecw[j + 2]; a3 = ecw[j + 3]; }
    while (rem >= 4) {
        int jn = j + 4;
        int remn = rem - 4;
        int2 b0, b1, b2, b3;
        if (remn >= 4) {  // prefetch next batch under current gathers
            b0 = ecw[jn]; b1 = ecw[jn + 1]; b2 = ecw[jn + 2]; b3 = ecw[jn + 3];
        } else {
            b0 = b1 = b2 = b3 = make_int2(0, 0);
        }
        float g0 = bf2f(h_in[(size_t)a0.x * kD + lane]);
        float g1 = bf2f(h_in[(size_t)a1.x * kD + lane]);
        float g2 = bf2f(h_in[(size_t)a2.x * kD + lane]);
        float g3 = bf2f(h_in[(size_t)a3.x * kD + lane]);
        float w0 = __int_as_float(a0.y) * dinv[a0.x];
        float w1 = __int_as_float(a1.y) * dinv[a1.x];
        float w2 = __int_as_float(a2.y) * dinv[a2.x];
        float w3 = __int_as_float(a3.y) * dinv[a3.x];
        acc = fmaf(w0, g0, acc);
        acc = fmaf(w1, g1, acc);
        acc = fmaf(w2, g2, acc);
        acc = fmaf(w3, g3, acc);
        a0 = b0; a1 = b1; a2 = b2; a3 = b3;
        j = jn; rem = remn;
    }
    for (; rem > 0; --rem, ++j) {
        int2 v = ecw[j];
        acc = fmaf(__int_as_float(v.y) * dinv[v.x],
                   bf2f(h_in[(size_t)v.x * kD + lane]), acc);
    }
    writeout(node, lane, di, acc);
}

__global__ __launch_bounds__(256) void k_hop1(const int* __restrict__ start,
                                              const int2* __restrict__ ecw,
                                              const float* __restrict__ dinv,
                                              const unsigned short* __restrict__ h_in,
                                              unsigned short* __restrict__ h_out, int n) {
    hop_body(start, ecw, dinv, h_in, n,
             [=](int node, int lane, float di, float acc) {
                 h_out[(size_t)node * kD + lane] = f2bf(di * acc);
             });
}

__global__ __launch_bounds__(256) void k_hop2(const int* __restrict__ start,
                                              const int2* __restrict__ ecw,
                                              const float* __restrict__ dinv,
                                              const unsigned short* __restrict__ h_in,
                                              const float* __restrict__ bias,
                                              float* __restrict__ out, int n) {
    hop_body(start, ecw, dinv, h_in, n,
             [=](int node, int lane, float di, float acc) {
                 out[(size_t)node * kD + lane] = fmaf(di, acc, bias[lane]);
             });
}

extern "C" void kernel_launch(void* const* d_in, const int* in_sizes, int n_in,
                              void* d_out, int out_size, void* d_ws, size_t ws_size,
                              hipStream_t stream) {
    const float* x    = (const float*)d_in[0];   // (N, 64)
    const int*   ei   = (const int*)d_in[1];     // (2, E)
    const float* ew   = (const float*)d_in[2];   // (E,)
    const float* W    = (const float*)d_in[3];   // (64, 64)
    const float* bias = (const float*)d_in[4];   // (64,)
    const int E = in_sizes[1] / 2;
    const int* row = ei;       // destination
    const int* col = ei + E;   // source

    const int nblk = (E + CHUNK - 1) / CHUNK;  // pass-A blocks (245 @ E=1M)

    // ws layout (1KB-aligned): base[256] | bc[NBUCK*nblk] | start[kN+1] |
    // dinv[kN] | ecw[E] int2 | y bf16 | h1 bf16 (tmp aliases h1)   (~35 MB)
    char* ws = (char*)d_ws;
    auto alloc = [&](size_t bytes) {
        char* p = ws;
        ws += ((bytes + 1023) & ~(size_t)1023);
        return p;
    };
    int*            base  = (int*)alloc(sizeof(int) * 256);
    int*            bc    = (int*)alloc(sizeof(int) * (size_t)NBUCK * nblk);
    int*            start = (int*)alloc(sizeof(int) * (kN + 1));
    float*          dinv  = (float*)alloc(sizeof(float) * kN);
    int2*           ecw   = (int2*)alloc(sizeof(int2) * (size_t)E);
    unsigned short* y     = (unsigned short*)alloc(sizeof(short) * (size_t)kN * kD);
    unsigned short* h1    = (unsigned short*)alloc(sizeof(short) * (size_t)kN * kD);
    int2*           tmp   = (int2*)h1;  // bucket-major staging, dead before hop1

    // dense linear first: y = x @ W (bf16)
    k_xw<<<(kN + 255) / 256, 256, 0, stream>>>(x, W, y, kN);

    // CSR build (no per-edge global atomics)
    kA_count<<<nblk, 256, 0, stream>>>(row, bc, nblk, E);
    kA_scan<<<1, 256, 0, stream>>>(bc, base, nblk);
    kA_place<<<nblk, 256, 0, stream>>>(row, col, ew, bc, base, nblk, tmp, E);
    kB_sort<<<NBUCK, 512, 0, stream>>>(tmp, base, ecw, start, dinv, E);

    // 2 gather hops (normalization folded in)
    k_hop1<<<(kN + 3) / 4, 256, 0, stream>>>(start, ecw, dinv, y, h1, kN);
    k_hop2<<<(kN + 3) / 4, 256, 0, stream>>>(start, ecw, dinv, h1, bias,
                                             (float*)d_out, kN);
}

// Round 9
// 174.825 us; speedup vs baseline: 1.4698x; 1.4698x over previous
//
#include <hip/hip_runtime.h>

// SGC: out = A_norm^2 (x W) + bias   (linearity: A^2 x W = A^2 (xW)).
// N=100000 nodes, E=1000000 edges, D=64 features, fp32 in/out.
// CSR build = two-level LDS-binned counting sort, ZERO per-edge global
// atomics. Round-7: pass-A2 scan parallelized (was 89us serial-in-1-block).
//   kA_count: per-block LDS hist over 196 coarse buckets -> bc[bucket][block]
//   kA_scanB: 1 block/bucket: parallel scan of its per-block counts
//   kA_scanT: 1 block: exclusive scan of bucket totals -> base[]
//   kA_place: LDS-staged bucket-major placement, coalesced run flush -> tmp
//   kB_sort : per-bucket fine sort (512-node range) -> ecw + start[] + dinv
// Hops: atomic-free gathers, bf16 intermediates, ecw-stream pipelining.

constexpr int kN = 100000;
constexpr int kD = 64;
constexpr int BSHIFT = 9;                    // 512 nodes per coarse bucket
constexpr int NBUCK = (kN + 511) >> BSHIFT;  // 196
constexpr int CHUNK = 4096;                  // pass-A edges per block

__device__ __forceinline__ float bf2f(unsigned short u) {
    return __uint_as_float(((unsigned)u) << 16);
}
__device__ __forceinline__ unsigned short f2bf(float f) {  // RNE
    unsigned b = __float_as_uint(f);
    b += 0x7FFF + ((b >> 16) & 1);
    return (unsigned short)(b >> 16);
}

// ---- pass A1: per-block bucket histogram (no global atomics) ----
__global__ __launch_bounds__(256) void kA_count(const int* __restrict__ row,
                                                int* __restrict__ bc, int nblk, int E) {
    __shared__ int hist[256];
    int t = threadIdx.x;
    hist[t] = 0;
    __syncthreads();
    int g0 = blockIdx.x * CHUNK;
    int n = min(CHUNK, E - g0);
    for (int i = t; i < n; i += 256) {
        atomicAdd(&hist[row[g0 + i] >> BSHIFT], 1);
    }
    __syncthreads();
    if (t < NBUCK) bc[t * nblk + blockIdx.x] = hist[t];
}

// ---- pass A2a: per-bucket parallel exclusive scan over blocks ----
// grid = NBUCK blocks; bucket b's counts bc[b*nblk + 0..nblk) -> exclusive,
// tot[b] = bucket total. Handles nblk > 256 via per-thread segments.
__global__ __launch_bounds__(256) void kA_scanB(int* __restrict__ bc,
                                                int* __restrict__ tot, int nblk) {
    __shared__ int sh[256];
    int b = blockIdx.x;
    int t = threadIdx.x;
    int* p = bc + (size_t)b * nblk;
    int ipt = (nblk + 255) >> 8;  // items per thread (1 for nblk<=256)
    int s0 = t * ipt;
    int s1 = min(s0 + ipt, nblk);
    int lsum = 0;
    for (int k = s0; k < s1; ++k) lsum += p[k];
    sh[t] = lsum;
    __syncthreads();
    for (int off = 1; off < 256; off <<= 1) {
        int add = (t >= off) ? sh[t - off] : 0;
        __syncthreads();
        sh[t] += add;
        __syncthreads();
    }
    int run = sh[t] - lsum;  // exclusive prefix of this thread's segment
    for (int k = s0; k < s1; ++k) {
        int v = p[k];
        p[k] = run;
        run += v;
    }
    if (t == 255) tot[b] = sh[255];
}

// ---- pass A2b: exclusive scan of bucket totals -> base[] ----
__global__ __launch_bounds__(256) void kA_scanT(const int* __restrict__ tot,
                                                int* __restrict__ base) {
    __shared__ int sh[256];
    int t = threadIdx.x;
    int v = (t < NBUCK) ? tot[t] : 0;
    sh[t] = v;
    __syncthreads();
    for (int off = 1; off < 256; off <<= 1) {
        int add = (t >= off) ? sh[t - off] : 0;
        __syncthreads();
        sh[t] += add;
        __syncthreads();
    }
    if (t < NBUCK) base[t] = sh[t] - v;
}

// ---- pass A3: bucket-major placement via LDS staging, coalesced run flush
// tmp[pos] = { col | (row&511)<<17 , w_bits }
__global__ __launch_bounds__(256) void kA_place(const int* __restrict__ row,
                                                const int* __restrict__ col,
                                                const float* __restrict__ w,
                                                const int* __restrict__ bc,
                                                const int* __restrict__ base, int nblk,
                                                int2* __restrict__ tmp, int E) {
    __shared__ int hist[256];
    __shared__ int lbase[256];
    __shared__ int gb[256];
    __shared__ int cur[256];
    __shared__ int2 stage[CHUNK];
    __shared__ unsigned char bkt[CHUNK];
    int t = threadIdx.x;
    hist[t] = 0;
    __syncthreads();
    int g0 = blockIdx.x * CHUNK;
    int n = min(CHUNK, E - g0);
    for (int i = t; i < n; i += 256) {
        atomicAdd(&hist[row[g0 + i] >> BSHIFT], 1);
    }
    __syncthreads();
    // exclusive scan hist -> lbase (local bucket starts within this chunk)
    int v = hist[t];
    lbase[t] = v;
    __syncthreads();
    for (int off = 1; off < 256; off <<= 1) {
        int add = (t >= off) ? lbase[t - off] : 0;
        __syncthreads();
        lbase[t] += add;
        __syncthreads();
    }
    int excl = lbase[t] - v;
    __syncthreads();
    lbase[t] = excl;
    cur[t] = excl;
    if (t < NBUCK) gb[t] = base[t] + bc[t * nblk + blockIdx.x];  // block's run start
    __syncthreads();
    // place edges bucket-major in LDS (LDS atomics only)
    for (int i = t; i < n; i += 256) {
        int r = row[g0 + i];
        int c = col[g0 + i];
        float wv = w[g0 + i];
        int b = r >> BSHIFT;
        int lp = atomicAdd(&cur[b], 1);
        stage[lp] = make_int2(c | ((r & 511) << 17), __float_as_int(wv));
        bkt[lp] = (unsigned char)b;
    }
    __syncthreads();
    // flush: consecutive i within a bucket run -> consecutive global addresses
    for (int i = t; i < n; i += 256) {
        int b = bkt[i];
        tmp[gb[b] + (i - lbase[b])] = stage[i];
    }
}

// ---- pass B: per-bucket fine counting sort + start[] + fused deg/dinv ----
__global__ __launch_bounds__(512) void kB_sort(const int2* __restrict__ tmp,
                                               const int* __restrict__ base,
                                               int2* __restrict__ ecw,
                                               int* __restrict__ start,
                                               float* __restrict__ dinv, int E) {
    __shared__ int hist[512];
    __shared__ int lstart[512];
    __shared__ int cur[512];
    int b = blockIdx.x;
    int t = threadIdx.x;
    int gbase = base[b];
    int gend = (b == NBUCK - 1) ? E : base[b + 1];
    int size = gend - gbase;
    int node0 = b << BSHIFT;
    int nloc = min(512, kN - node0);
    hist[t] = 0;
    __syncthreads();
    for (int i = t; i < size; i += 512) {
        atomicAdd(&hist[(tmp[gbase + i].x >> 17) & 511], 1);
    }
    __syncthreads();
    // exclusive scan hist -> lstart
    int v = hist[t];
    lstart[t] = v;
    __syncthreads();
    for (int off = 1; off < 512; off <<= 1) {
        int add = (t >= off) ? lstart[t - off] : 0;
        __syncthreads();
        lstart[t] += add;
        __syncthreads();
    }
    int excl = lstart[t] - v;
    __syncthreads();
    lstart[t] = excl;
    cur[t] = excl;
    __syncthreads();
    if (t < nloc) start[node0 + t] = gbase + excl;
    if (b == 0 && t == 0) start[kN] = E;
    // scatter within bucket (writes stay in one XCD's L2 -> no amplification)
    for (int i = t; i < size; i += 512) {
        int2 e = tmp[gbase + i];
        int rl = (e.x >> 17) & 511;
        int lp = atomicAdd(&cur[rl], 1);
        ecw[gbase + lp] = make_int2(e.x & 0x1FFFF, e.y);
    }
    __syncthreads();
    // fused deg: dinv = rsqrt(1 + sum w) over this node's (L2-hot) segment
    if (t < nloc) {
        int s = gbase + lstart[t];
        int eend = s + hist[t];
        float d = 1.0f;
        for (int j = s; j < eend; ++j) d += __int_as_float(ecw[j].y);
        dinv[node0 + t] = (d > 0.0f) ? rsqrtf(d) : 0.0f;
    }
}

// ---- y = x @ W  (fp32 in, bf16 out). thread = row, W staged in LDS. ----
__global__ __launch_bounds__(256) void k_xw(const float* __restrict__ x,
                                            const float* __restrict__ W,
                                            unsigned short* __restrict__ y, int n) {
    __shared__ float Ws[kD * kD];
    for (int i = threadIdx.x; i < kD * kD; i += 256) Ws[i] = W[i];
    __syncthreads();
    int r = blockIdx.x * 256 + threadIdx.x;
    if (r >= n) return;
    float hr[kD];
    const float4* hp = reinterpret_cast<const float4*>(x + (size_t)r * kD);
#pragma unroll
    for (int k4 = 0; k4 < kD / 4; ++k4) {
        float4 v = hp[k4];
        hr[k4 * 4 + 0] = v.x;
        hr[k4 * 4 + 1] = v.y;
        hr[k4 * 4 + 2] = v.z;
        hr[k4 * 4 + 3] = v.w;
    }
    ushort4* op = reinterpret_cast<ushort4*>(y + (size_t)r * kD);
#pragma unroll
    for (int jb = 0; jb < kD / 4; ++jb) {
        float a0 = 0.0f, a1 = 0.0f, a2 = 0.0f, a3 = 0.0f;
#pragma unroll
        for (int k = 0; k < kD; ++k) {
            float hv = hr[k];
            a0 = fmaf(hv, Ws[k * kD + jb * 4 + 0], a0);
            a1 = fmaf(hv, Ws[k * kD + jb * 4 + 1], a1);
            a2 = fmaf(hv, Ws[k * kD + jb * 4 + 2], a2);
            a3 = fmaf(hv, Ws[k * kD + jb * 4 + 3], a3);
        }
        ushort4 o;
        o.x = f2bf(a0); o.y = f2bf(a1); o.z = f2bf(a2); o.w = f2bf(a3);
        op[jb] = o;
    }
}

// ---- software-pipelined gather hop body: 1 wave/node, lane=feature ----
template <typename OutWriter>
__device__ __forceinline__ void hop_body(const int* __restrict__ start,
                                         const int2* __restrict__ ecw,
                                         const float* __restrict__ dinv,
                                         const unsigned short* __restrict__ h_in,
                                         int n, OutWriter writeout) {
    int node = blockIdx.x * 4 + (threadIdx.x >> 6);
    int lane = threadIdx.x & 63;
    if (node >= n) return;  // wave-uniform (1 wave = 1 node)
    float di = dinv[node];
    float self = bf2f(h_in[(size_t)node * kD + lane]);
    float acc = di * self;
    int s = start[node], e = start[node + 1];
    int j = s;
    int rem = e - s;
    int2 a0, a1, a2, a3;
    if (rem >= 4) { a0 = ecw[j]; a1 = ecw[j + 1]; a2 = ecw[j + 2]; a3 = ecw[j + 3]; }
    while (rem >= 4) {
        int jn = j + 4;
        int remn = rem - 4;
        int2 b0, b1, b2, b3;
        if (remn >= 4) {  // prefetch next batch under current gathers
            b0 = ecw[jn]; b1 = ecw[jn + 1]; b2 = ecw[jn + 2]; b3 = ecw[jn + 3];
        } else {
            b0 = b1 = b2 = b3 = make_int2(0, 0);
        }
        float g0 = bf2f(h_in[(size_t)a0.x * kD + lane]);
        float g1 = bf2f(h_in[(size_t)a1.x * kD + lane]);
        float g2 = bf2f(h_in[(size_t)a2.x * kD + lane]);
        float g3 = bf2f(h_in[(size_t)a3.x * kD + lane]);
        float w0 = __int_as_float(a0.y) * dinv[a0.x];
        float w1 = __int_as_float(a1.y) * dinv[a1.x];
        float w2 = __int_as_float(a2.y) * dinv[a2.x];
        float w3 = __int_as_float(a3.y) * dinv[a3.x];
        acc = fmaf(w0, g0, acc);
        acc = fmaf(w1, g1, acc);
        acc = fmaf(w2, g2, acc);
        acc = fmaf(w3, g3, acc);
        a0 = b0; a1 = b1; a2 = b2; a3 = b3;
        j = jn; rem = remn;
    }
    for (; rem > 0; --rem, ++j) {
        int2 v = ecw[j];
        acc = fmaf(__int_as_float(v.y) * dinv[v.x],
                   bf2f(h_in[(size_t)v.x * kD + lane]), acc);
    }
    writeout(node, lane, di, acc);
}

__global__ __launch_bounds__(256) void k_hop1(const int* __restrict__ start,
                                              const int2* __restrict__ ecw,
                                              const float* __restrict__ dinv,
                                              const unsigned short* __restrict__ h_in,
                                              unsigned short* __restrict__ h_out, int n) {
    hop_body(start, ecw, dinv, h_in, n,
             [=](int node, int lane, float di, float acc) {
                 h_out[(size_t)node * kD + lane] = f2bf(di * acc);
             });
}

__global__ __launch_bounds__(256) void k_hop2(const int* __restrict__ start,
                                              const int2* __restrict__ ecw,
                                              const float* __restrict__ dinv,
                                              const unsigned short* __restrict__ h_in,
                                              const float* __restrict__ bias,
                                              float* __restrict__ out, int n) {
    hop_body(start, ecw, dinv, h_in, n,
             [=](int node, int lane, float di, float acc) {
                 out[(size_t)node * kD + lane] = fmaf(di, acc, bias[lane]);
             });
}

extern "C" void kernel_launch(void* const* d_in, const int* in_sizes, int n_in,
                              void* d_out, int out_size, void* d_ws, size_t ws_size,
                              hipStream_t stream) {
    const float* x    = (const float*)d_in[0];   // (N, 64)
    const int*   ei   = (const int*)d_in[1];     // (2, E)
    const float* ew   = (const float*)d_in[2];   // (E,)
    const float* W    = (const float*)d_in[3];   // (64, 64)
    const float* bias = (const float*)d_in[4];   // (64,)
    const int E = in_sizes[1] / 2;
    const int* row = ei;       // destination
    const int* col = ei + E;   // source

    const int nblk = (E + CHUNK - 1) / CHUNK;  // pass-A blocks (245 @ E=1M)

    // ws layout (1KB-aligned): base[256] | tot[256] | bc[NBUCK*nblk] |
    // start[kN+1] | dinv[kN] | ecw[E] int2 | y bf16 | h1 bf16 (tmp aliases h1)
    char* ws = (char*)d_ws;
    auto alloc = [&](size_t bytes) {
        char* p = ws;
        ws += ((bytes + 1023) & ~(size_t)1023);
        return p;
    };
    int*            base  = (int*)alloc(sizeof(int) * 256);
    int*            tot   = (int*)alloc(sizeof(int) * 256);
    int*            bc    = (int*)alloc(sizeof(int) * (size_t)NBUCK * nblk);
    int*            start = (int*)alloc(sizeof(int) * (kN + 1));
    float*          dinv  = (float*)alloc(sizeof(float) * kN);
    int2*           ecw   = (int2*)alloc(sizeof(int2) * (size_t)E);
    unsigned short* y     = (unsigned short*)alloc(sizeof(short) * (size_t)kN * kD);
    unsigned short* h1    = (unsigned short*)alloc(sizeof(short) * (size_t)kN * kD);
    int2*           tmp   = (int2*)h1;  // bucket-major staging, dead before hop1

    // dense linear first: y = x @ W (bf16)
    k_xw<<<(kN + 255) / 256, 256, 0, stream>>>(x, W, y, kN);

    // CSR build (no per-edge global atomics)
    kA_count<<<nblk, 256, 0, stream>>>(row, bc, nblk, E);
    kA_scanB<<<NBUCK, 256, 0, stream>>>(bc, tot, nblk);
    kA_scanT<<<1, 256, 0, stream>>>(tot, base);
    kA_place<<<nblk, 256, 0, stream>>>(row, col, ew, bc, base, nblk, tmp, E);
    kB_sort<<<NBUCK, 512, 0, stream>>>(tmp, base, ecw, start, dinv, E);

    // 2 gather hops (normalization folded in)
    k_hop1<<<(kN + 3) / 4, 256, 0, stream>>>(start, ecw, dinv, y, h1, kN);
    k_hop2<<<(kN + 3) / 4, 256, 0, stream>>>(start, ecw, dinv, h1, bias,
                                             (float*)d_out, kN);
}

// Round 10
// 154.211 us; speedup vs baseline: 1.6663x; 1.1337x over previous
//
#include <hip/hip_runtime.h>

// SGC: out = A_norm^2 (x W) + bias   (linearity: A^2 x W = A^2 (xW)).
// N=100000 nodes, E=1000000 edges, D=64 features, fp32 in/out.
// CSR build = two-level LDS-binned counting sort, ZERO per-edge global
// atomics. Round-10: edge weights PRE-NORMALIZED (k_norm per-bucket pass)
// so hops carry no dinv gathers; hop per-wave state scalarized via
// readfirstlane so ecw/start loads leave the VMEM pipe.
//   kA_count: per-block LDS hist over 196 coarse buckets -> bc[bucket][block]
//   kA_scanB: 1 block/bucket: parallel scan of its per-block counts
//   kA_scanT: 1 block: exclusive scan of bucket totals -> base[]
//   kA_place: LDS-staged bucket-major placement, coalesced run flush -> tmp
//   kB_sort : per-bucket fine sort -> ecw (col|rl<<17, raw w) + start + dinv
//   k_norm  : per-bucket: ecw -> {col, dinv[row]*w*dinv[col]}
// Hops: atomic-free gathers, bf16 intermediates.

constexpr int kN = 100000;
constexpr int kD = 64;
constexpr int BSHIFT = 9;                    // 512 nodes per coarse bucket
constexpr int NBUCK = (kN + 511) >> BSHIFT;  // 196
constexpr int CHUNK = 4096;                  // pass-A edges per block

__device__ __forceinline__ float bf2f(unsigned short u) {
    return __uint_as_float(((unsigned)u) << 16);
}
__device__ __forceinline__ unsigned short f2bf(float f) {  // RNE
    unsigned b = __float_as_uint(f);
    b += 0x7FFF + ((b >> 16) & 1);
    return (unsigned short)(b >> 16);
}

// ---- pass A1: per-block bucket histogram (no global atomics) ----
__global__ __launch_bounds__(256) void kA_count(const int* __restrict__ row,
                                                int* __restrict__ bc, int nblk, int E) {
    __shared__ int hist[256];
    int t = threadIdx.x;
    hist[t] = 0;
    __syncthreads();
    int g0 = blockIdx.x * CHUNK;
    int n = min(CHUNK, E - g0);
    for (int i = t; i < n; i += 256) {
        atomicAdd(&hist[row[g0 + i] >> BSHIFT], 1);
    }
    __syncthreads();
    if (t < NBUCK) bc[t * nblk + blockIdx.x] = hist[t];
}

// ---- pass A2a: per-bucket parallel exclusive scan over blocks ----
__global__ __launch_bounds__(256) void kA_scanB(int* __restrict__ bc,
                                                int* __restrict__ tot, int nblk) {
    __shared__ int sh[256];
    int b = blockIdx.x;
    int t = threadIdx.x;
    int* p = bc + (size_t)b * nblk;
    int ipt = (nblk + 255) >> 8;  // items per thread (1 for nblk<=256)
    int s0 = t * ipt;
    int s1 = min(s0 + ipt, nblk);
    int lsum = 0;
    for (int k = s0; k < s1; ++k) lsum += p[k];
    sh[t] = lsum;
    __syncthreads();
    for (int off = 1; off < 256; off <<= 1) {
        int add = (t >= off) ? sh[t - off] : 0;
        __syncthreads();
        sh[t] += add;
        __syncthreads();
    }
    int run = sh[t] - lsum;  // exclusive prefix of this thread's segment
    for (int k = s0; k < s1; ++k) {
        int v = p[k];
        p[k] = run;
        run += v;
    }
    if (t == 255) tot[b] = sh[255];
}

// ---- pass A2b: exclusive scan of bucket totals -> base[] ----
__global__ __launch_bounds__(256) void kA_scanT(const int* __restrict__ tot,
                                                int* __restrict__ base) {
    __shared__ int sh[256];
    int t = threadIdx.x;
    int v = (t < NBUCK) ? tot[t] : 0;
    sh[t] = v;
    __syncthreads();
    for (int off = 1; off < 256; off <<= 1) {
        int add = (t >= off) ? sh[t - off] : 0;
        __syncthreads();
        sh[t] += add;
        __syncthreads();
    }
    if (t < NBUCK) base[t] = sh[t] - v;
}

// ---- pass A3: bucket-major placement via LDS staging, coalesced run flush
// tmp[pos] = { col | (row&511)<<17 , w_bits }
__global__ __launch_bounds__(256) void kA_place(const int* __restrict__ row,
                                                const int* __restrict__ col,
                                                const float* __restrict__ w,
                                                const int* __restrict__ bc,
                                                const int* __restrict__ base, int nblk,
                                                int2* __restrict__ tmp, int E) {
    __shared__ int hist[256];
    __shared__ int lbase[256];
    __shared__ int gb[256];
    __shared__ int cur[256];
    __shared__ int2 stage[CHUNK];
    __shared__ unsigned char bkt[CHUNK];
    int t = threadIdx.x;
    hist[t] = 0;
    __syncthreads();
    int g0 = blockIdx.x * CHUNK;
    int n = min(CHUNK, E - g0);
    for (int i = t; i < n; i += 256) {
        atomicAdd(&hist[row[g0 + i] >> BSHIFT], 1);
    }
    __syncthreads();
    // exclusive scan hist -> lbase (local bucket starts within this chunk)
    int v = hist[t];
    lbase[t] = v;
    __syncthreads();
    for (int off = 1; off < 256; off <<= 1) {
        int add = (t >= off) ? lbase[t - off] : 0;
        __syncthreads();
        lbase[t] += add;
        __syncthreads();
    }
    int excl = lbase[t] - v;
    __syncthreads();
    lbase[t] = excl;
    cur[t] = excl;
    if (t < NBUCK) gb[t] = base[t] + bc[t * nblk + blockIdx.x];  // block's run start
    __syncthreads();
    // place edges bucket-major in LDS (LDS atomics only)
    for (int i = t; i < n; i += 256) {
        int r = row[g0 + i];
        int c = col[g0 + i];
        float wv = w[g0 + i];
        int b = r >> BSHIFT;
        int lp = atomicAdd(&cur[b], 1);
        stage[lp] = make_int2(c | ((r & 511) << 17), __float_as_int(wv));
        bkt[lp] = (unsigned char)b;
    }
    __syncthreads();
    // flush: consecutive i within a bucket run -> consecutive global addresses
    for (int i = t; i < n; i += 256) {
        int b = bkt[i];
        tmp[gb[b] + (i - lbase[b])] = stage[i];
    }
}

// ---- pass B: per-bucket fine counting sort + start[] + fused deg/dinv ----
// ecw keeps {col | rl<<17, raw w}; k_norm finalizes weights afterwards.
__global__ __launch_bounds__(512) void kB_sort(const int2* __restrict__ tmp,
                                               const int* __restrict__ base,
                                               int2* __restrict__ ecw,
                                               int* __restrict__ start,
                                               float* __restrict__ dinv, int E) {
    __shared__ int hist[512];
    __shared__ int lstart[512];
    __shared__ int cur[512];
    int b = blockIdx.x;
    int t = threadIdx.x;
    int gbase = base[b];
    int gend = (b == NBUCK - 1) ? E : base[b + 1];
    int size = gend - gbase;
    int node0 = b << BSHIFT;
    int nloc = min(512, kN - node0);
    hist[t] = 0;
    __syncthreads();
    for (int i = t; i < size; i += 512) {
        atomicAdd(&hist[(tmp[gbase + i].x >> 17) & 511], 1);
    }
    __syncthreads();
    // exclusive scan hist -> lstart
    int v = hist[t];
    lstart[t] = v;
    __syncthreads();
    for (int off = 1; off < 512; off <<= 1) {
        int add = (t >= off) ? lstart[t - off] : 0;
        __syncthreads();
        lstart[t] += add;
        __syncthreads();
    }
    int excl = lstart[t] - v;
    __syncthreads();
    lstart[t] = excl;
    cur[t] = excl;
    __syncthreads();
    if (t < nloc) start[node0 + t] = gbase + excl;
    if (b == 0 && t == 0) start[kN] = E;
    // scatter within bucket (keep rl bits for k_norm)
    for (int i = t; i < size; i += 512) {
        int2 e = tmp[gbase + i];
        int rl = (e.x >> 17) & 511;
        int lp = atomicAdd(&cur[rl], 1);
        ecw[gbase + lp] = e;
    }
    __syncthreads();
    // fused deg: dinv = rsqrt(1 + sum w) over this node's (L2-hot) segment
    if (t < nloc) {
        int s = gbase + lstart[t];
        int eend = s + hist[t];
        float d = 1.0f;
        for (int j = s; j < eend; ++j) d += __int_as_float(ecw[j].y);
        dinv[node0 + t] = (d > 0.0f) ? rsqrtf(d) : 0.0f;
    }
}

// ---- finalize weights: ecw = {col, dinv[row]*w*dinv[col]} (all dinv ready)
__global__ __launch_bounds__(256) void k_norm(const int* __restrict__ base,
                                              const float* __restrict__ dinv,
                                              int2* __restrict__ ecw, int E) {
    int b = blockIdx.x;
    int gbase = base[b];
    int gend = (b == NBUCK - 1) ? E : base[b + 1];
    int node0 = b << BSHIFT;
    for (int i = gbase + threadIdx.x; i < gend; i += 256) {
        int2 v = ecw[i];
        int c = v.x & 0x1FFFF;
        int rl = (v.x >> 17) & 511;
        float wn = dinv[node0 + rl] * __int_as_float(v.y) * dinv[c];
        ecw[i] = make_int2(c, __float_as_int(wn));
    }
}

// ---- y = x @ W  (fp32 in, bf16 out). thread = row, W staged in LDS. ----
__global__ __launch_bounds__(256) void k_xw(const float* __restrict__ x,
                                            const float* __restrict__ W,
                                            unsigned short* __restrict__ y, int n) {
    __shared__ float Ws[kD * kD];
    for (int i = threadIdx.x; i < kD * kD; i += 256) Ws[i] = W[i];
    __syncthreads();
    int r = blockIdx.x * 256 + threadIdx.x;
    if (r >= n) return;
    float hr[kD];
    const float4* hp = reinterpret_cast<const float4*>(x + (size_t)r * kD);
#pragma unroll
    for (int k4 = 0; k4 < kD / 4; ++k4) {
        float4 v = hp[k4];
        hr[k4 * 4 + 0] = v.x;
        hr[k4 * 4 + 1] = v.y;
        hr[k4 * 4 + 2] = v.z;
        hr[k4 * 4 + 3] = v.w;
    }
    ushort4* op = reinterpret_cast<ushort4*>(y + (size_t)r * kD);
#pragma unroll
    for (int jb = 0; jb < kD / 4; ++jb) {
        float a0 = 0.0f, a1 = 0.0f, a2 = 0.0f, a3 = 0.0f;
#pragma unroll
        for (int k = 0; k < kD; ++k) {
            float hv = hr[k];
            a0 = fmaf(hv, Ws[k * kD + jb * 4 + 0], a0);
            a1 = fmaf(hv, Ws[k * kD + jb * 4 + 1], a1);
            a2 = fmaf(hv, Ws[k * kD + jb * 4 + 2], a2);
            a3 = fmaf(hv, Ws[k * kD + jb * 4 + 3], a3);
        }
        ushort4 o;
        o.x = f2bf(a0); o.y = f2bf(a1); o.z = f2bf(a2); o.w = f2bf(a3);
        op[jb] = o;
    }
}

// ---- gather hop: 1 wave/node (scalarized), lane = feature ----
// acc = dinv^2*h[node] + sum_j w'_j * h[col_j]
template <typename OutWriter>
__device__ __forceinline__ void hop_body(const int* __restrict__ start,
                                         const int2* __restrict__ ecw,
                                         const float* __restrict__ dinv,
                                         const unsigned short* __restrict__ h_in,
                                         int n, OutWriter writeout) {
    // readfirstlane -> node & all edge-stream addresses live in SGPRs
    int node = blockIdx.x * 4 + __builtin_amdgcn_readfirstlane(threadIdx.x >> 6);
    int lane = threadIdx.x & 63;
    if (node >= n) return;  // wave-uniform (1 wave = 1 node)
    float di = dinv[node];
    float self = bf2f(h_in[(size_t)node * kD + lane]);
    float acc = di * di * self;
    int s = start[node], e = start[node + 1];
    int j = s;
    for (; j + 7 < e; j += 8) {
        int2 v0 = ecw[j + 0], v1 = ecw[j + 1], v2 = ecw[j + 2], v3 = ecw[j + 3];
        int2 v4 = ecw[j + 4], v5 = ecw[j + 5], v6 = ecw[j + 6], v7 = ecw[j + 7];
        float g0 = bf2f(h_in[(size_t)v0.x * kD + lane]);
        float g1 = bf2f(h_in[(size_t)v1.x * kD + lane]);
        float g2 = bf2f(h_in[(size_t)v2.x * kD + lane]);
        float g3 = bf2f(h_in[(size_t)v3.x * kD + lane]);
        float g4 = bf2f(h_in[(size_t)v4.x * kD + lane]);
        float g5 = bf2f(h_in[(size_t)v5.x * kD + lane]);
        float g6 = bf2f(h_in[(size_t)v6.x * kD + lane]);
        float g7 = bf2f(h_in[(size_t)v7.x * kD + lane]);
        acc = fmaf(__int_as_float(v0.y), g0, acc);
        acc = fmaf(__int_as_float(v1.y), g1, acc);
        acc = fmaf(__int_as_float(v2.y), g2, acc);
        acc = fmaf(__int_as_float(v3.y), g3, acc);
        acc = fmaf(__int_as_float(v4.y), g4, acc);
        acc = fmaf(__int_as_float(v5.y), g5, acc);
        acc = fmaf(__int_as_float(v6.y), g6, acc);
        acc = fmaf(__int_as_float(v7.y), g7, acc);
    }
    for (; j + 3 < e; j += 4) {
        int2 v0 = ecw[j + 0], v1 = ecw[j + 1], v2 = ecw[j + 2], v3 = ecw[j + 3];
        float g0 = bf2f(h_in[(size_t)v0.x * kD + lane]);
        float g1 = bf2f(h_in[(size_t)v1.x * kD + lane]);
        float g2 = bf2f(h_in[(size_t)v2.x * kD + lane]);
        float g3 = bf2f(h_in[(size_t)v3.x * kD + lane]);
        acc = fmaf(__int_as_float(v0.y), g0, acc);
        acc = fmaf(__int_as_float(v1.y), g1, acc);
        acc = fmaf(__int_as_float(v2.y), g2, acc);
        acc = fmaf(__int_as_float(v3.y), g3, acc);
    }
    for (; j < e; ++j) {
        int2 v = ecw[j];
        acc = fmaf(__int_as_float(v.y), bf2f(h_in[(size_t)v.x * kD + lane]), acc);
    }
    writeout(node, lane, di, acc);
}

__global__ __launch_bounds__(256) void k_hop1(const int* __restrict__ start,
                                              const int2* __restrict__ ecw,
                                              const float* __restrict__ dinv,
                                              const unsigned short* __restrict__ h_in,
                                              unsigned short* __restrict__ h_out, int n) {
    hop_body(start, ecw, dinv, h_in, n,
             [=](int node, int lane, float di, float acc) {
                 h_out[(size_t)node * kD + lane] = f2bf(acc);
             });
}

__global__ __launch_bounds__(256) void k_hop2(const int* __restrict__ start,
                                              const int2* __restrict__ ecw,
                                              const float* __restrict__ dinv,
                                              const unsigned short* __restrict__ h_in,
                                              const float* __restrict__ bias,
                                              float* __restrict__ out, int n) {
    hop_body(start, ecw, dinv, h_in, n,
             [=](int node, int lane, float di, float acc) {
                 out[(size_t)node * kD + lane] = acc + bias[lane];
             });
}

extern "C" void kernel_launch(void* const* d_in, const int* in_sizes, int n_in,
                              void* d_out, int out_size, void* d_ws, size_t ws_size,
                              hipStream_t stream) {
    const float* x    = (const float*)d_in[0];   // (N, 64)
    const int*   ei   = (const int*)d_in[1];     // (2, E)
    const float* ew   = (const float*)d_in[2];   // (E,)
    const float* W    = (const float*)d_in[3];   // (64, 64)
    const float* bias = (const float*)d_in[4];   // (64,)
    const int E = in_sizes[1] / 2;
    const int* row = ei;       // destination
    const int* col = ei + E;   // source

    const int nblk = (E + CHUNK - 1) / CHUNK;  // pass-A blocks (245 @ E=1M)

    // ws layout (1KB-aligned): base[256] | tot[256] | bc[NBUCK*nblk] |
    // start[kN+1] | dinv[kN] | ecw[E] int2 | y bf16 | h1 bf16 (tmp aliases h1)
    char* ws = (char*)d_ws;
    auto alloc = [&](size_t bytes) {
        char* p = ws;
        ws += ((bytes + 1023) & ~(size_t)1023);
        return p;
    };
    int*            base  = (int*)alloc(sizeof(int) * 256);
    int*            tot   = (int*)alloc(sizeof(int) * 256);
    int*            bc    = (int*)alloc(sizeof(int) * (size_t)NBUCK * nblk);
    int*            start = (int*)alloc(sizeof(int) * (kN + 1));
    float*          dinv  = (float*)alloc(sizeof(float) * kN);
    int2*           ecw   = (int2*)alloc(sizeof(int2) * (size_t)E);
    unsigned short* y     = (unsigned short*)alloc(sizeof(short) * (size_t)kN * kD);
    unsigned short* h1    = (unsigned short*)alloc(sizeof(short) * (size_t)kN * kD);
    int2*           tmp   = (int2*)h1;  // bucket-major staging, dead before hop1

    // dense linear first: y = x @ W (bf16)
    k_xw<<<(kN + 255) / 256, 256, 0, stream>>>(x, W, y, kN);

    // CSR build (no per-edge global atomics)
    kA_count<<<nblk, 256, 0, stream>>>(row, bc, nblk, E);
    kA_scanB<<<NBUCK, 256, 0, stream>>>(bc, tot, nblk);
    kA_scanT<<<1, 256, 0, stream>>>(tot, base);
    kA_place<<<nblk, 256, 0, stream>>>(row, col, ew, bc, base, nblk, tmp, E);
    kB_sort<<<NBUCK, 512, 0, stream>>>(tmp, base, ecw, start, dinv, E);
    k_norm<<<NBUCK, 256, 0, stream>>>(base, dinv, ecw, E);

    // 2 gather hops (weights fully pre-normalized)
    k_hop1<<<(kN + 3) / 4, 256, 0, stream>>>(start, ecw, dinv, y, h1, kN);
    k_hop2<<<(kN + 3) / 4, 256, 0, stream>>>(start, ecw, dinv, h1, bias,
                                             (float*)d_out, kN);
}

// Round 11
// 144.764 us; speedup vs baseline: 1.7750x; 1.0653x over previous
//
#include <hip/hip_runtime.h>

// SGC: out = A_norm^2 (x W) + bias   (linearity: A^2 x W = A^2 (xW)).
// N=100000 nodes, E=1000000 edges, D=64 features, fp32 in/out.
// CSR build = two-level LDS-binned counting sort, ZERO per-edge global
// atomics. Round-11: k_xw rewritten (W-cols in VGPRs, X-rows in LDS,
// broadcast reads) -- old version burned 1.6GB of LDS traffic at 7%
// occupancy. ecw stores byte offsets (col<<7) so hop gathers are
// SGPR-base + 32-bit voffset with ~2 VALU each.

constexpr int kN = 100000;
constexpr int kD = 64;
constexpr int BSHIFT = 9;                    // 512 nodes per coarse bucket
constexpr int NBUCK = (kN + 511) >> BSHIFT;  // 196
constexpr int CHUNK = 4096;                  // pass-A edges per block
constexpr int XW_ROWS = 128;                 // k_xw rows per block

__device__ __forceinline__ float bf2f(unsigned short u) {
    return __uint_as_float(((unsigned)u) << 16);
}
__device__ __forceinline__ unsigned short f2bf(float f) {  // RNE
    unsigned b = __float_as_uint(f);
    b += 0x7FFF + ((b >> 16) & 1);
    return (unsigned short)(b >> 16);
}

// ---- pass A1: per-block bucket histogram (no global atomics) ----
__global__ __launch_bounds__(256) void kA_count(const int* __restrict__ row,
                                                int* __restrict__ bc, int nblk, int E) {
    __shared__ int hist[256];
    int t = threadIdx.x;
    hist[t] = 0;
    __syncthreads();
    int g0 = blockIdx.x * CHUNK;
    int n = min(CHUNK, E - g0);
    for (int i = t; i < n; i += 256) {
        atomicAdd(&hist[row[g0 + i] >> BSHIFT], 1);
    }
    __syncthreads();
    if (t < NBUCK) bc[t * nblk + blockIdx.x] = hist[t];
}

// ---- pass A2a: per-bucket parallel exclusive scan over blocks ----
__global__ __launch_bounds__(256) void kA_scanB(int* __restrict__ bc,
                                                int* __restrict__ tot, int nblk) {
    __shared__ int sh[256];
    int b = blockIdx.x;
    int t = threadIdx.x;
    int* p = bc + (size_t)b * nblk;
    int ipt = (nblk + 255) >> 8;  // items per thread (1 for nblk<=256)
    int s0 = t * ipt;
    int s1 = min(s0 + ipt, nblk);
    int lsum = 0;
    for (int k = s0; k < s1; ++k) lsum += p[k];
    sh[t] = lsum;
    __syncthreads();
    for (int off = 1; off < 256; off <<= 1) {
        int add = (t >= off) ? sh[t - off] : 0;
        __syncthreads();
        sh[t] += add;
        __syncthreads();
    }
    int run = sh[t] - lsum;  // exclusive prefix of this thread's segment
    for (int k = s0; k < s1; ++k) {
        int v = p[k];
        p[k] = run;
        run += v;
    }
    if (t == 255) tot[b] = sh[255];
}

// ---- pass A2b: exclusive scan of bucket totals -> base[] ----
__global__ __launch_bounds__(256) void kA_scanT(const int* __restrict__ tot,
                                                int* __restrict__ base) {
    __shared__ int sh[256];
    int t = threadIdx.x;
    int v = (t < NBUCK) ? tot[t] : 0;
    sh[t] = v;
    __syncthreads();
    for (int off = 1; off < 256; off <<= 1) {
        int add = (t >= off) ? sh[t - off] : 0;
        __syncthreads();
        sh[t] += add;
        __syncthreads();
    }
    if (t < NBUCK) base[t] = sh[t] - v;
}

// ---- pass A3: bucket-major placement via LDS staging, coalesced run flush
// tmp[pos] = { col | (row&511)<<17 , w_bits }
__global__ __launch_bounds__(256) void kA_place(const int* __restrict__ row,
                                                const int* __restrict__ col,
                                                const float* __restrict__ w,
                                                const int* __restrict__ bc,
                                                const int* __restrict__ base, int nblk,
                                                int2* __restrict__ tmp, int E) {
    __shared__ int hist[256];
    __shared__ int lbase[256];
    __shared__ int gb[256];
    __shared__ int cur[256];
    __shared__ int2 stage[CHUNK];
    __shared__ unsigned char bkt[CHUNK];
    int t = threadIdx.x;
    hist[t] = 0;
    __syncthreads();
    int g0 = blockIdx.x * CHUNK;
    int n = min(CHUNK, E - g0);
    for (int i = t; i < n; i += 256) {
        atomicAdd(&hist[row[g0 + i] >> BSHIFT], 1);
    }
    __syncthreads();
    // exclusive scan hist -> lbase (local bucket starts within this chunk)
    int v = hist[t];
    lbase[t] = v;
    __syncthreads();
    for (int off = 1; off < 256; off <<= 1) {
        int add = (t >= off) ? lbase[t - off] : 0;
        __syncthreads();
        lbase[t] += add;
        __syncthreads();
    }
    int excl = lbase[t] - v;
    __syncthreads();
    lbase[t] = excl;
    cur[t] = excl;
    if (t < NBUCK) gb[t] = base[t] + bc[t * nblk + blockIdx.x];  // block's run start
    __syncthreads();
    // place edges bucket-major in LDS (LDS atomics only)
    for (int i = t; i < n; i += 256) {
        int r = row[g0 + i];
        int c = col[g0 + i];
        float wv = w[g0 + i];
        int b = r >> BSHIFT;
        int lp = atomicAdd(&cur[b], 1);
        stage[lp] = make_int2(c | ((r & 511) << 17), __float_as_int(wv));
        bkt[lp] = (unsigned char)b;
    }
    __syncthreads();
    // flush: consecutive i within a bucket run -> consecutive global addresses
    for (int i = t; i < n; i += 256) {
        int b = bkt[i];
        tmp[gb[b] + (i - lbase[b])] = stage[i];
    }
}

// ---- pass B: per-bucket fine counting sort + start[] + fused deg/dinv ----
// ecw keeps {col | rl<<17, raw w}; k_norm finalizes weights afterwards.
__global__ __launch_bounds__(512) void kB_sort(const int2* __restrict__ tmp,
                                               const int* __restrict__ base,
                                               int2* __restrict__ ecw,
                                               int* __restrict__ start,
                                               float* __restrict__ dinv, int E) {
    __shared__ int hist[512];
    __shared__ int lstart[512];
    __shared__ int cur[512];
    int b = blockIdx.x;
    int t = threadIdx.x;
    int gbase = base[b];
    int gend = (b == NBUCK - 1) ? E : base[b + 1];
    int size = gend - gbase;
    int node0 = b << BSHIFT;
    int nloc = min(512, kN - node0);
    hist[t] = 0;
    __syncthreads();
    for (int i = t; i < size; i += 512) {
        atomicAdd(&hist[(tmp[gbase + i].x >> 17) & 511], 1);
    }
    __syncthreads();
    // exclusive scan hist -> lstart
    int v = hist[t];
    lstart[t] = v;
    __syncthreads();
    for (int off = 1; off < 512; off <<= 1) {
        int add = (t >= off) ? lstart[t - off] : 0;
        __syncthreads();
        lstart[t] += add;
        __syncthreads();
    }
    int excl = lstart[t] - v;
    __syncthreads();
    lstart[t] = excl;
    cur[t] = excl;
    __syncthreads();
    if (t < nloc) start[node0 + t] = gbase + excl;
    if (b == 0 && t == 0) start[kN] = E;
    // scatter within bucket (keep rl bits for k_norm)
    for (int i = t; i < size; i += 512) {
        int2 e = tmp[gbase + i];
        int rl = (e.x >> 17) & 511;
        int lp = atomicAdd(&cur[rl], 1);
        ecw[gbase + lp] = e;
    }
    __syncthreads();
    // fused deg: dinv = rsqrt(1 + sum w) over this node's (L2-hot) segment
    if (t < nloc) {
        int s = gbase + lstart[t];
        int eend = s + hist[t];
        float d = 1.0f;
        for (int j = s; j < eend; ++j) d += __int_as_float(ecw[j].y);
        dinv[node0 + t] = (d > 0.0f) ? rsqrtf(d) : 0.0f;
    }
}

// ---- finalize weights: ecw = {byte offset col<<7, dinv[row]*w*dinv[col]} ----
__global__ __launch_bounds__(256) void k_norm(const int* __restrict__ base,
                                              const float* __restrict__ dinv,
                                              int2* __restrict__ ecw, int E) {
    int b = blockIdx.x;
    int gbase = base[b];
    int gend = (b == NBUCK - 1) ? E : base[b + 1];
    int node0 = b << BSHIFT;
    for (int i = gbase + threadIdx.x; i < gend; i += 256) {
        int2 v = ecw[i];
        int c = v.x & 0x1FFFF;
        int rl = (v.x >> 17) & 511;
        float wn = dinv[node0 + rl] * __int_as_float(v.y) * dinv[c];
        ecw[i] = make_int2(c << 7, __float_as_int(wn));  // col*kD*2 byte offset
    }
}

// ---- y = x @ W (fp32 in, bf16 out) ----
// lane = output column (W column in 64 VGPRs); 128 x-rows staged in LDS;
// per row: 16 broadcast b128 LDS reads + 64 FMAs; 2 rows in flight.
__global__ __launch_bounds__(256) void k_xw(const float* __restrict__ x,
                                            const float* __restrict__ W,
                                            unsigned short* __restrict__ y, int n) {
    __shared__ float Xs[XW_ROWS][kD];
    int t = threadIdx.x;
    int lane = t & 63;
    int wv = t >> 6;  // wave id 0..3
    int row0 = blockIdx.x * XW_ROWS;
    // W column 'lane' -> registers (coalesced: consecutive lanes, consecutive addr)
    float Wc[kD];
#pragma unroll
    for (int k = 0; k < kD; ++k) Wc[k] = W[k * kD + lane];
    // stage 128 rows of x into LDS (float4 coalesced), zero-pad past n
    for (int i = t; i < XW_ROWS * (kD / 4); i += 256) {
        int r = i >> 4;
        int q = i & 15;
        float4 v = make_float4(0.0f, 0.0f, 0.0f, 0.0f);
        if (row0 + r < n)
            v = *reinterpret_cast<const float4*>(x + (size_t)(row0 + r) * kD + q * 4);
        *reinterpret_cast<float4*>(&Xs[r][q * 4]) = v;
    }
    __syncthreads();
    int rbase = wv * 32;  // this wave's 32 rows
#pragma unroll
    for (int rr = 0; rr < 32; rr += 2) {
        int r0 = rbase + rr;
        float acc0 = 0.0f, acc1 = 0.0f;
#pragma unroll
        for (int q = 0; q < 16; ++q) {  // broadcast reads: all lanes same addr
            float4 a = *reinterpret_cast<const float4*>(&Xs[r0][q * 4]);
            float4 b = *reinterpret_cast<const float4*>(&Xs[r0 + 1][q * 4]);
            acc0 = fmaf(a.x, Wc[q * 4 + 0], acc0);
            acc1 = fmaf(b.x, Wc[q * 4 + 0], acc1);
            acc0 = fmaf(a.y, Wc[q * 4 + 1], acc0);
            acc1 = fmaf(b.y, Wc[q * 4 + 1], acc1);
            acc0 = fmaf(a.z, Wc[q * 4 + 2], acc0);
            acc1 = fmaf(b.z, Wc[q * 4 + 2], acc1);
            acc0 = fmaf(a.w, Wc[q * 4 + 3], acc0);
            acc1 = fmaf(b.w, Wc[q * 4 + 3], acc1);
        }
        int gr = row0 + r0;
        if (gr < n) y[(size_t)gr * kD + lane] = f2bf(acc0);
        if (gr + 1 < n) y[(size_t)(gr + 1) * kD + lane] = f2bf(acc1);
    }
}

// ---- gather hop: 1 wave/node (scalarized), lane = feature ----
// ecw.x is a byte offset (col*128); gather = h_base + (ecw.x + lane*2).
template <typename OutWriter>
__device__ __forceinline__ void hop_body(const int* __restrict__ start,
                                         const int2* __restrict__ ecw,
                                         const float* __restrict__ dinv,
                                         const unsigned short* __restrict__ h_in,
                                         int n, OutWriter writeout) {
    int node = blockIdx.x * 4 + __builtin_amdgcn_readfirstlane(threadIdx.x >> 6);
    int lane = threadIdx.x & 63;
    if (node >= n) return;  // wave-uniform (1 wave = 1 node)
    const char* hb = (const char*)h_in;
    int lo = lane << 1;  // lane byte offset, loop-invariant
    float di = dinv[node];
    float self = bf2f(h_in[(size_t)node * kD + lane]);
    float acc = di * di * self;
    int s = start[node], e = start[node + 1];
    int j = s;
    for (; j + 7 < e; j += 8) {
        int2 v0 = ecw[j + 0], v1 = ecw[j + 1], v2 = ecw[j + 2], v3 = ecw[j + 3];
        int2 v4 = ecw[j + 4], v5 = ecw[j + 5], v6 = ecw[j + 6], v7 = ecw[j + 7];
        float g0 = bf2f(*(const unsigned short*)(hb + (unsigned)(v0.x + lo)));
        float g1 = bf2f(*(const unsigned short*)(hb + (unsigned)(v1.x + lo)));
        float g2 = bf2f(*(const unsigned short*)(hb + (unsigned)(v2.x + lo)));
        float g3 = bf2f(*(const unsigned short*)(hb + (unsigned)(v3.x + lo)));
        float g4 = bf2f(*(const unsigned short*)(hb + (unsigned)(v4.x + lo)));
        float g5 = bf2f(*(const unsigned short*)(hb + (unsigned)(v5.x + lo)));
        float g6 = bf2f(*(const unsigned short*)(hb + (unsigned)(v6.x + lo)));
        float g7 = bf2f(*(const unsigned short*)(hb + (unsigned)(v7.x + lo)));
        acc = fmaf(__int_as_float(v0.y), g0, acc);
        acc = fmaf(__int_as_float(v1.y), g1, acc);
        acc = fmaf(__int_as_float(v2.y), g2, acc);
        acc = fmaf(__int_as_float(v3.y), g3, acc);
        acc = fmaf(__int_as_float(v4.y), g4, acc);
        acc = fmaf(__int_as_float(v5.y), g5, acc);
        acc = fmaf(__int_as_float(v6.y), g6, acc);
        acc = fmaf(__int_as_float(v7.y), g7, acc);
    }
    for (; j + 3 < e; j += 4) {
        int2 v0 = ecw[j + 0], v1 = ecw[j + 1], v2 = ecw[j + 2], v3 = ecw[j + 3];
        float g0 = bf2f(*(const unsigned short*)(hb + (unsigned)(v0.x + lo)));
        float g1 = bf2f(*(const unsigned short*)(hb + (unsigned)(v1.x + lo)));
        float g2 = bf2f(*(const unsigned short*)(hb + (unsigned)(v2.x + lo)));
        float g3 = bf2f(*(const unsigned short*)(hb + (unsigned)(v3.x + lo)));
        acc = fmaf(__int_as_float(v0.y), g0, acc);
        acc = fmaf(__int_as_float(v1.y), g1, acc);
        acc = fmaf(__int_as_float(v2.y), g2, acc);
        acc = fmaf(__int_as_float(v3.y), g3, acc);
    }
    for (; j < e; ++j) {
        int2 v = ecw[j];
        acc = fmaf(__int_as_float(v.y),
                   bf2f(*(const unsigned short*)(hb + (unsigned)(v.x + lo))), acc);
    }
    writeout(node, lane, di, acc);
}

__global__ __launch_bounds__(256) void k_hop1(const int* __restrict__ start,
                                              const int2* __restrict__ ecw,
                                              const float* __restrict__ dinv,
                                              const unsigned short* __restrict__ h_in,
                                              unsigned short* __restrict__ h_out, int n) {
    hop_body(start, ecw, dinv, h_in, n,
             [=](int node, int lane, float di, float acc) {
                 h_out[(size_t)node * kD + lane] = f2bf(acc);
             });
}

__global__ __launch_bounds__(256) void k_hop2(const int* __restrict__ start,
                                              const int2* __restrict__ ecw,
                                              const float* __restrict__ dinv,
                                              const unsigned short* __restrict__ h_in,
                                              const float* __restrict__ bias,
                                              float* __restrict__ out, int n) {
    hop_body(start, ecw, dinv, h_in, n,
             [=](int node, int lane, float di, float acc) {
                 out[(size_t)node * kD + lane] = acc + bias[lane];
             });
}

extern "C" void kernel_launch(void* const* d_in, const int* in_sizes, int n_in,
                              void* d_out, int out_size, void* d_ws, size_t ws_size,
                              hipStream_t stream) {
    const float* x    = (const float*)d_in[0];   // (N, 64)
    const int*   ei   = (const int*)d_in[1];     // (2, E)
    const float* ew   = (const float*)d_in[2];   // (E,)
    const float* W    = (const float*)d_in[3];   // (64, 64)
    const float* bias = (const float*)d_in[4];   // (64,)
    const int E = in_sizes[1] / 2;
    const int* row = ei;       // destination
    const int* col = ei + E;   // source

    const int nblk = (E + CHUNK - 1) / CHUNK;  // pass-A blocks (245 @ E=1M)

    // ws layout (1KB-aligned): base[256] | tot[256] | bc[NBUCK*nblk] |
    // start[kN+1] | dinv[kN] | ecw[E] int2 | y bf16 | h1 bf16 (tmp aliases h1)
    char* ws = (char*)d_ws;
    auto alloc = [&](size_t bytes) {
        char* p = ws;
        ws += ((bytes + 1023) & ~(size_t)1023);
        return p;
    };
    int*            base  = (int*)alloc(sizeof(int) * 256);
    int*            tot   = (int*)alloc(sizeof(int) * 256);
    int*            bc    = (int*)alloc(sizeof(int) * (size_t)NBUCK * nblk);
    int*            start = (int*)alloc(sizeof(int) * (kN + 1));
    float*          dinv  = (float*)alloc(sizeof(float) * kN);
    int2*           ecw   = (int2*)alloc(sizeof(int2) * (size_t)E);
    unsigned short* y     = (unsigned short*)alloc(sizeof(short) * (size_t)kN * kD);
    unsigned short* h1    = (unsigned short*)alloc(sizeof(short) * (size_t)kN * kD);
    int2*           tmp   = (int2*)h1;  // bucket-major staging, dead before hop1

    // dense linear first: y = x @ W (bf16)
    k_xw<<<(kN + XW_ROWS - 1) / XW_ROWS, 256, 0, stream>>>(x, W, y, kN);

    // CSR build (no per-edge global atomics)
    kA_count<<<nblk, 256, 0, stream>>>(row, bc, nblk, E);
    kA_scanB<<<NBUCK, 256, 0, stream>>>(bc, tot, nblk);
    kA_scanT<<<1, 256, 0, stream>>>(tot, base);
    kA_place<<<nblk, 256, 0, stream>>>(row, col, ew, bc, base, nblk, tmp, E);
    kB_sort<<<NBUCK, 512, 0, stream>>>(tmp, base, ecw, start, dinv, E);
    k_norm<<<NBUCK, 256, 0, stream>>>(base, dinv, ecw, E);

    // 2 gather hops (weights fully pre-normalized, byte-offset cols)
    k_hop1<<<(kN + 3) / 4, 256, 0, stream>>>(start, ecw, dinv, y, h1, kN);
    k_hop2<<<(kN + 3) / 4, 256, 0, stream>>>(start, ecw, dinv, h1, bias,
                                             (float*)d_out, kN);
}